// Round 8
// baseline (302.411 us; speedup 1.0000x reference)
//
#include <hip/hip_runtime.h>

#define N_NODES 200000
#define N_EDGES 600000
#define N_GRAPHS 10000
#define F_NODE 32
#define HDIM 128
#define BN_EPS 1e-5f

typedef unsigned short ushort_t;
typedef unsigned int uint_t;
typedef __attribute__((ext_vector_type(8))) short short8;
typedef __attribute__((ext_vector_type(4))) float f32x4;

__device__ __forceinline__ ushort_t f2bf(float f) {
    uint_t u = __builtin_bit_cast(uint_t, f);
    u += 0x7FFFu + ((u >> 16) & 1u);   // RNE
    return (ushort_t)(u >> 16);
}
__device__ __forceinline__ float bf2f(ushort_t h) {
    uint_t u = ((uint_t)h) << 16;
    return __builtin_bit_cast(float, u);
}

// ---------------- zero fill ----------------
__global__ __launch_bounds__(256) void fill_zero_k(uint_t* __restrict__ p, long long n)
{
    long long gid = (long long)blockIdx.x * blockDim.x + threadIdx.x;
    long long stride = (long long)gridDim.x * blockDim.x;
    for (long long i = gid; i < n; i += stride) p[i] = 0u;
}

// ---------------- prep: all 6 weight permutes + x->bf16, one kernel ----------------
// wp regions (ushort elems): w1_1 @0 (4096), w2_1 @4096, w1_2 @20480, w2_2 @36864,
//                            w1_3 @53248, w2_3 @69632 (each 16384). Total 86016.
__global__ __launch_bounds__(256) void prep_k(
    const float* __restrict__ w1_1, const float* __restrict__ w2_1,
    const float* __restrict__ w1_2, const float* __restrict__ w2_2,
    const float* __restrict__ w1_3, const float* __restrict__ w2_3,
    ushort_t* __restrict__ wp, const float* __restrict__ x, ushort_t* __restrict__ xbf)
{
    int gid = blockIdx.x * 256 + threadIdx.x;
    if (gid < 86016) {
        const float* w; int lidx; int K;
        if (gid < 4096)       { w = w1_1; lidx = gid;         K = 32; }
        else if (gid < 20480) { w = w2_1; lidx = gid - 4096;  K = 128; }
        else if (gid < 36864) { w = w1_2; lidx = gid - 20480; K = 128; }
        else if (gid < 53248) { w = w2_2; lidx = gid - 36864; K = 128; }
        else if (gid < 69632) { w = w1_3; lidx = gid - 53248; K = 128; }
        else                  { w = w2_3; lidx = gid - 69632; K = 128; }
        int KS = K / 32;
        int idx = lidx;
        int j = idx & 7; idx >>= 3;
        int lane = idx & 63; idx >>= 6;
        int ks = idx % KS;
        int ntg = idx / KS;
        int k = ks * 32 + ((lane >> 4) << 3) + j;
        int n = ntg * 16 + (lane & 15);
        wp[gid] = f2bf(w[k * HDIM + n]);
    } else {
        long long i8 = gid - 86016;
        if (i8 < (long long)N_NODES * F_NODE / 8) {
            const float4* ip = (const float4*)(x + i8 * 8);
            float4 a = ip[0], b = ip[1];
            uint4 u;
            u.x = (uint_t)f2bf(a.x) | ((uint_t)f2bf(a.y) << 16);
            u.y = (uint_t)f2bf(a.z) | ((uint_t)f2bf(a.w) << 16);
            u.z = (uint_t)f2bf(b.x) | ((uint_t)f2bf(b.y) << 16);
            u.w = (uint_t)f2bf(b.z) | ((uint_t)f2bf(b.w) << 16);
            *reinterpret_cast<uint4*>(xbf + i8 * 8) = u;
        }
    }
}

// ---------------- CSR build ----------------
__global__ __launch_bounds__(256) void hist_k(const int* __restrict__ dst, int* __restrict__ deg)
{
    int e = blockIdx.x * 256 + threadIdx.x;
    if (e < N_EDGES) atomicAdd(&deg[dst[e]], 1);
}

__global__ __launch_bounds__(256) void scan_blocks_k(
    const int* __restrict__ deg, int* __restrict__ incl, int* __restrict__ bsum)
{
    __shared__ int sh[256];
    int i = blockIdx.x * 256 + threadIdx.x;
    int v = (i < N_NODES) ? deg[i] : 0;
    sh[threadIdx.x] = v;
    __syncthreads();
    #pragma unroll
    for (int off = 1; off < 256; off <<= 1) {
        int t = (threadIdx.x >= off) ? sh[threadIdx.x - off] : 0;
        __syncthreads();
        sh[threadIdx.x] += t;
        __syncthreads();
    }
    if (i < N_NODES) incl[i] = sh[threadIdx.x];
    if (threadIdx.x == 255) bsum[blockIdx.x] = sh[255];
}

__global__ __launch_bounds__(256) void scan_bsum_k(int* __restrict__ bsum, int nb)
{
    __shared__ int sh[256];
    int run = 0;
    for (int base = 0; base < nb; base += 256) {
        int i = base + threadIdx.x;
        int v = (i < nb) ? bsum[i] : 0;
        sh[threadIdx.x] = v;
        __syncthreads();
        #pragma unroll
        for (int off = 1; off < 256; off <<= 1) {
            int t = (threadIdx.x >= off) ? sh[threadIdx.x - off] : 0;
            __syncthreads();
            sh[threadIdx.x] += t;
            __syncthreads();
        }
        if (i < nb) bsum[i] = run + sh[threadIdx.x] - v;  // exclusive
        run += sh[255];
        __syncthreads();
    }
}

__global__ __launch_bounds__(256) void finalize_csr_k(
    const int* __restrict__ deg, const int* __restrict__ incl,
    const int* __restrict__ bsum, int* __restrict__ rowptr, int* __restrict__ cursor)
{
    int i = blockIdx.x * 256 + threadIdx.x;
    if (i >= N_NODES) return;
    int v = incl[i] + bsum[blockIdx.x];
    rowptr[i + 1] = v;
    cursor[i] = v - deg[i];
    if (i == 0) rowptr[0] = 0;
}

__global__ __launch_bounds__(256) void fill_edges_k(
    const int* __restrict__ src, const int* __restrict__ dst,
    int* __restrict__ cursor, int* __restrict__ col)
{
    int e = blockIdx.x * 256 + threadIdx.x;
    if (e >= N_EDGES) return;
    int pos = atomicAdd(&cursor[dst[e]], 1);
    col[pos] = src[e];
}

// ---------------- fused GIN layer ----------------
// Gather: 4 threads/row = FS feature-splits x ES edge-splits; partial sums merged
// via __shfl_xor (register-only). Serial depth per row = deg/ES.
template<int K, int FS, int ES, bool POOL>
__global__ __launch_bounds__(256) void fused_layer_k(
    const ushort_t* __restrict__ xin, const int* __restrict__ rowptr,
    const int* __restrict__ col, const ushort_t* __restrict__ wp1,
    const float* __restrict__ b1, const float* __restrict__ gamma,
    const float* __restrict__ beta, const float* __restrict__ rmean,
    const float* __restrict__ rvar, const ushort_t* __restrict__ wp2,
    const float* __restrict__ b2, ushort_t* __restrict__ out,
    const int* __restrict__ batch, float* __restrict__ pooled)
{
    constexpr int KS1 = K / 32;        // K-steps of GEMM1
    constexpr int KS2 = 4;             // GEMM2 is always K=128
    constexpr int LDA = K + 8;         // bf16 stage leading dim
    constexpr int LDT = HDIM + 8;      // T leading dim = 136 (bf16)
    constexpr int FPT = K / FS;        // features per thread
    constexpr int NV  = FPT / 8;       // uint4 loads per edge per thread
    constexpr int CH  = FPT / ES;      // features stored per eh-thread
    __shared__ ushort_t A_lds[64 * LDT];
    __shared__ int batch_l[64];

    const int tid  = threadIdx.x;
    const int lane = tid & 63;
    const int wid  = tid >> 6;
    const int wm   = wid >> 1;
    const int wn   = wid & 1;
    const long long m0 = (long long)blockIdx.x * 64;

    if (POOL && tid < 64) batch_l[tid] = batch[m0 + tid];

    // ---- gather-stage ----
    {
        const int row = tid >> 2;
        const int sub = tid & 3;
        const int fh  = sub / ES;
        const int eh  = sub % ES;
        const int fq  = fh * FPT;
        long long n = m0 + row;
        float acc[FPT];
        if (eh == 0) {
            const uint4* xp = (const uint4*)(xin + n * (long long)K + fq);
            #pragma unroll
            for (int v = 0; v < NV; ++v) {
                uint4 u = xp[v];
                acc[v*8+0]=bf2f(u.x&0xffff); acc[v*8+1]=bf2f(u.x>>16);
                acc[v*8+2]=bf2f(u.y&0xffff); acc[v*8+3]=bf2f(u.y>>16);
                acc[v*8+4]=bf2f(u.z&0xffff); acc[v*8+5]=bf2f(u.z>>16);
                acc[v*8+6]=bf2f(u.w&0xffff); acc[v*8+7]=bf2f(u.w>>16);
            }
        } else {
            #pragma unroll
            for (int f = 0; f < FPT; ++f) acc[f] = 0.f;
        }
        const int p0 = rowptr[n], p1 = rowptr[n + 1];
        for (int p = p0 + eh; p < p1; p += ES) {
            long long s = col[p];
            const uint4* sp = (const uint4*)(xin + s * (long long)K + fq);
            uint4 u[NV];
            #pragma unroll
            for (int v = 0; v < NV; ++v) u[v] = sp[v];
            #pragma unroll
            for (int v = 0; v < NV; ++v) {
                acc[v*8+0]+=bf2f(u[v].x&0xffff); acc[v*8+1]+=bf2f(u[v].x>>16);
                acc[v*8+2]+=bf2f(u[v].y&0xffff); acc[v*8+3]+=bf2f(u[v].y>>16);
                acc[v*8+4]+=bf2f(u[v].z&0xffff); acc[v*8+5]+=bf2f(u[v].z>>16);
                acc[v*8+6]+=bf2f(u[v].w&0xffff); acc[v*8+7]+=bf2f(u[v].w>>16);
            }
        }
        // merge edge-partials across the ES lanes (register shuffle, exact f32)
        #pragma unroll
        for (int m = 1; m < ES; m <<= 1) {
            #pragma unroll
            for (int f = 0; f < FPT; ++f)
                acc[f] += __shfl_xor(acc[f], m, 64);
        }
        // each eh-thread stores its CH-feature chunk (static indices only)
        #pragma unroll
        for (int ee = 0; ee < ES; ++ee) {
            if (eh == ee) {
                #pragma unroll
                for (int f = 0; f < CH; f += 2) {
                    uint_t pk = (uint_t)f2bf(acc[ee*CH + f]) |
                                ((uint_t)f2bf(acc[ee*CH + f + 1]) << 16);
                    *reinterpret_cast<uint_t*>(&A_lds[row * LDA + fq + ee*CH + f]) = pk;
                }
            }
        }
    }
    __syncthreads();

    // ---- GEMM1 K-loop ----
    f32x4 acc1[2][4] = {};
    {
        short8 bfrag[4][KS1];
        #pragma unroll
        for (int nt = 0; nt < 4; ++nt)
            #pragma unroll
            for (int ks = 0; ks < KS1; ++ks) {
                int ntg = wn * 4 + nt;
                bfrag[nt][ks] = *reinterpret_cast<const short8*>(
                    wp1 + ((((ntg * KS1) + ks) * 64 + lane) << 3));
            }
        #pragma unroll
        for (int ks = 0; ks < KS1; ++ks) {
            short8 afrag[2];
            #pragma unroll
            for (int mt = 0; mt < 2; ++mt) {
                int row = wm * 32 + mt * 16 + (lane & 15);
                int c   = ks * 32 + ((lane >> 4) << 3);
                afrag[mt] = *reinterpret_cast<const short8*>(&A_lds[row * LDA + c]);
            }
            #pragma unroll
            for (int mt = 0; mt < 2; ++mt)
                #pragma unroll
                for (int nt = 0; nt < 4; ++nt)
                    acc1[mt][nt] = __builtin_amdgcn_mfma_f32_16x16x32_bf16(
                        afrag[mt], bfrag[nt][ks], acc1[mt][nt], 0, 0, 0);
        }
    }
    __syncthreads();   // all waves done reading A_lds

    // ---- BN + ReLU -> T into A_lds (LDT layout) ----
    #pragma unroll
    for (int nt = 0; nt < 4; ++nt) {
        int c = wn * 64 + nt * 16 + (lane & 15);
        float rs = rsqrtf(rvar[c] + BN_EPS);
        float scale = gamma[c] * rs;
        float shift = (b1[c] - rmean[c]) * scale + beta[c];
        #pragma unroll
        for (int mt = 0; mt < 2; ++mt) {
            int rowb = wm * 32 + mt * 16 + ((lane >> 4) << 2);
            #pragma unroll
            for (int r = 0; r < 4; ++r) {
                float v = fmaxf(acc1[mt][nt][r] * scale + shift, 0.f);
                A_lds[(rowb + r) * LDT + c] = f2bf(v);
            }
        }
    }
    __syncthreads();

    // ---- GEMM2 K-loop (K = 128 over T) ----
    f32x4 acc2[2][4] = {};
    {
        short8 bfrag[4][KS2];
        #pragma unroll
        for (int nt = 0; nt < 4; ++nt)
            #pragma unroll
            for (int ks = 0; ks < KS2; ++ks) {
                int ntg = wn * 4 + nt;
                bfrag[nt][ks] = *reinterpret_cast<const short8*>(
                    wp2 + ((((ntg * KS2) + ks) * 64 + lane) << 3));
            }
        #pragma unroll
        for (int ks = 0; ks < KS2; ++ks) {
            short8 afrag[2];
            #pragma unroll
            for (int mt = 0; mt < 2; ++mt) {
                int row = wm * 32 + mt * 16 + (lane & 15);
                int c   = ks * 32 + ((lane >> 4) << 3);
                afrag[mt] = *reinterpret_cast<const short8*>(&A_lds[row * LDT + c]);
            }
            #pragma unroll
            for (int mt = 0; mt < 2; ++mt)
                #pragma unroll
                for (int nt = 0; nt < 4; ++nt)
                    acc2[mt][nt] = __builtin_amdgcn_mfma_f32_16x16x32_bf16(
                        afrag[mt], bfrag[nt][ks], acc2[mt][nt], 0, 0, 0);
        }
    }

    if (!POOL) {
        #pragma unroll
        for (int nt = 0; nt < 4; ++nt) {
            int c = wn * 64 + nt * 16 + (lane & 15);
            float bias = b2[c];
            #pragma unroll
            for (int mt = 0; mt < 2; ++mt) {
                long long rowb = m0 + wm * 32 + mt * 16 + ((lane >> 4) << 2);
                #pragma unroll
                for (int r = 0; r < 4; ++r) {
                    float v = fmaxf(acc2[mt][nt][r] + bias, 0.f);
                    out[(rowb + r) * HDIM + c] = f2bf(v);
                }
            }
        }
    } else {
        __syncthreads();   // all waves done reading T
        #pragma unroll
        for (int nt = 0; nt < 4; ++nt) {
            int c = wn * 64 + nt * 16 + (lane & 15);
            float bias = b2[c];
            #pragma unroll
            for (int mt = 0; mt < 2; ++mt) {
                int rowb = wm * 32 + mt * 16 + ((lane >> 4) << 2);
                #pragma unroll
                for (int r = 0; r < 4; ++r) {
                    float v = fmaxf(acc2[mt][nt][r] + bias, 0.f);
                    A_lds[(rowb + r) * LDT + c] = f2bf(v);
                }
            }
        }
        __syncthreads();
        if (tid < HDIM) {
            int colw = tid;
            int curb = batch_l[0];
            float s = 0.f;
            #pragma unroll 8
            for (int r = 0; r < 64; ++r) {
                int b = batch_l[r];
                if (b != curb) {
                    atomicAdd(&pooled[(long long)curb * HDIM + colw], s);
                    curb = b; s = 0.f;
                }
                s += bf2f(A_lds[r * LDT + colw]);
            }
            atomicAdd(&pooled[(long long)curb * HDIM + colw], s);
        }
    }
}

// ---------------- head ----------------
__global__ __launch_bounds__(64) void fc_head_k(
    const float* __restrict__ pooled,
    const float* __restrict__ w_fc1, const float* __restrict__ b_fc1,
    const float* __restrict__ w_fc2, const float* __restrict__ b_fc2,
    float* __restrict__ out)
{
    int g = blockIdx.x;
    int j = threadIdx.x;   // 0..63
    __shared__ float p[HDIM];
    p[j]      = pooled[(long long)g * HDIM + j];
    p[j + 64] = pooled[(long long)g * HDIM + j + 64];
    __syncthreads();

    float acc = b_fc1[j];
    #pragma unroll 8
    for (int k = 0; k < HDIM; ++k) acc += p[k] * w_fc1[k * 64 + j];
    acc = fmaxf(acc, 0.f);

    float v = acc * w_fc2[j];
    #pragma unroll
    for (int off = 32; off > 0; off >>= 1) v += __shfl_down(v, off, 64);
    if (j == 0) out[g] = v + b_fc2[0];
}

extern "C" void kernel_launch(void* const* d_in, const int* in_sizes, int n_in,
                              void* d_out, int out_size, void* d_ws, size_t ws_size,
                              hipStream_t stream) {
    const float* x     = (const float*)d_in[0];
    const int*   ei    = (const int*)d_in[1];
    const int*   src   = ei;                // edge_index[0]
    const int*   dst   = ei + N_EDGES;      // edge_index[1]
    const int*   batch = (const int*)d_in[3];
    const float* L[3][8];
    for (int l = 0; l < 3; ++l)
        for (int p = 0; p < 8; ++p)
            L[l][p] = (const float*)d_in[4 + 8 * l + p];
    const float* w_fc1 = (const float*)d_in[30];
    const float* b_fc1 = (const float*)d_in[31];
    const float* w_fc2 = (const float*)d_in[32];
    const float* b_fc2 = (const float*)d_in[33];
    float* out = (float*)d_out;

    // ---- workspace layout (bytes); pooled|deg contiguous for single zero-fill ----
    char* base = (char*)d_ws;
    ushort_t* hA     = (ushort_t*)(base);                 // bf16 [N,128] 51.2 MB
    ushort_t* hB     = (ushort_t*)(base + 51200000);      // bf16 [N,128] 51.2 MB
    ushort_t* xbf    = (ushort_t*)(base + 102400000);     // bf16 [N,32] 12.8 MB
    float*    pooled = (float*)   (base + 115200000);     // f32 [G,128] 5.12 MB
    int*      deg    = (int*)     (base + 120320000);     // 800 KB (contiguous after pooled)
    int*      incl   = (int*)     (base + 121120000);     // 800 KB
    int*      bsum   = (int*)     (base + 121920000);     // 4 KB
    int*      rowptr = (int*)     (base + 121924096);     // 800,004 B
    int*      cursor = (int*)     (base + 122724112);     // 800 KB
    int*      colarr = (int*)     (base + 123524112);     // 2.4 MB
    ushort_t* wp     = (ushort_t*)(base + 125924112);     // 172 KB

    ushort_t* wp1_1 = wp;
    ushort_t* wp2_1 = wp + 4096;
    ushort_t* wp1_2 = wp + 20480;
    ushort_t* wp2_2 = wp + 36864;
    ushort_t* wp1_3 = wp + 53248;
    ushort_t* wp2_3 = wp + 69632;

    const int GEMM_GRID = N_NODES / 64;          // 3125
    const int NB_NODE   = (N_NODES + 255) / 256; // 782
    const int NB_EDGE   = (N_EDGES + 255) / 256; // 2344

    // ---- single zero-fill: pooled (1.28M f32) + deg (200k int), contiguous ----
    fill_zero_k<<<512, 256, 0, stream>>>((uint_t*)pooled,
        (long long)N_GRAPHS * HDIM + N_NODES);

    // ---- prep: all weight permutes + x->bf16 in one kernel ----
    {
        long long tot = 86016 + (long long)N_NODES * F_NODE / 8;
        prep_k<<<(int)((tot + 255) / 256), 256, 0, stream>>>(
            L[0][0], L[0][6], L[1][0], L[1][6], L[2][0], L[2][6], wp, x, xbf);
    }

    // ---- CSR build ----
    hist_k<<<NB_EDGE, 256, 0, stream>>>(dst, deg);
    scan_blocks_k<<<NB_NODE, 256, 0, stream>>>(deg, incl, bsum);
    scan_bsum_k<<<1, 256, 0, stream>>>(bsum, NB_NODE);
    finalize_csr_k<<<NB_NODE, 256, 0, stream>>>(deg, incl, bsum, rowptr, cursor);
    fill_edges_k<<<NB_EDGE, 256, 0, stream>>>(src, dst, cursor, colarr);

    // ---- 3 fused layers ----
    fused_layer_k<F_NODE, 1, 4, false><<<GEMM_GRID, 256, 0, stream>>>(
        xbf, rowptr, colarr, wp1_1, L[0][1], L[0][2], L[0][3], L[0][4], L[0][5],
        wp2_1, L[0][7], hA, nullptr, nullptr);
    fused_layer_k<HDIM, 2, 2, false><<<GEMM_GRID, 256, 0, stream>>>(
        hA, rowptr, colarr, wp1_2, L[1][1], L[1][2], L[1][3], L[1][4], L[1][5],
        wp2_2, L[1][7], hB, nullptr, nullptr);
    fused_layer_k<HDIM, 2, 2, true><<<GEMM_GRID, 256, 0, stream>>>(
        hB, rowptr, colarr, wp1_3, L[2][1], L[2][2], L[2][3], L[2][4], L[2][5],
        wp2_3, L[2][7], nullptr, batch, pooled);

    // ---- head ----
    fc_head_k<<<N_GRAPHS, 64, 0, stream>>>(pooled, w_fc1, b_fc1, w_fc2, b_fc2, out);
}

// Round 9
// 254.971 us; speedup vs baseline: 1.1861x; 1.1861x over previous
//
#include <hip/hip_runtime.h>

#define N_NODES 200000
#define N_EDGES 600000
#define N_GRAPHS 10000
#define F_NODE 32
#define HDIM 128
#define BN_EPS 1e-5f

typedef unsigned short ushort_t;
typedef unsigned int uint_t;
typedef __attribute__((ext_vector_type(8))) short short8;
typedef __attribute__((ext_vector_type(4))) float f32x4;

__device__ __forceinline__ ushort_t f2bf(float f) {
    uint_t u = __builtin_bit_cast(uint_t, f);
    u += 0x7FFFu + ((u >> 16) & 1u);   // RNE
    return (ushort_t)(u >> 16);
}
__device__ __forceinline__ float bf2f(ushort_t h) {
    uint_t u = ((uint_t)h) << 16;
    return __builtin_bit_cast(float, u);
}

// ---------------- zero fill ----------------
__global__ __launch_bounds__(256) void fill_zero_k(uint_t* __restrict__ p, long long n)
{
    long long gid = (long long)blockIdx.x * blockDim.x + threadIdx.x;
    long long stride = (long long)gridDim.x * blockDim.x;
    for (long long i = gid; i < n; i += stride) p[i] = 0u;
}

// ---------------- prep: all 6 weight permutes + x->bf16, one kernel ----------------
__global__ __launch_bounds__(256) void prep_k(
    const float* __restrict__ w1_1, const float* __restrict__ w2_1,
    const float* __restrict__ w1_2, const float* __restrict__ w2_2,
    const float* __restrict__ w1_3, const float* __restrict__ w2_3,
    ushort_t* __restrict__ wp, const float* __restrict__ x, ushort_t* __restrict__ xbf)
{
    int gid = blockIdx.x * 256 + threadIdx.x;
    if (gid < 86016) {
        const float* w; int lidx; int K;
        if (gid < 4096)       { w = w1_1; lidx = gid;         K = 32; }
        else if (gid < 20480) { w = w2_1; lidx = gid - 4096;  K = 128; }
        else if (gid < 36864) { w = w1_2; lidx = gid - 20480; K = 128; }
        else if (gid < 53248) { w = w2_2; lidx = gid - 36864; K = 128; }
        else if (gid < 69632) { w = w1_3; lidx = gid - 53248; K = 128; }
        else                  { w = w2_3; lidx = gid - 69632; K = 128; }
        int KS = K / 32;
        int idx = lidx;
        int j = idx & 7; idx >>= 3;
        int lane = idx & 63; idx >>= 6;
        int ks = idx % KS;
        int ntg = idx / KS;
        int k = ks * 32 + ((lane >> 4) << 3) + j;
        int n = ntg * 16 + (lane & 15);
        wp[gid] = f2bf(w[k * HDIM + n]);
    } else {
        long long i8 = gid - 86016;
        if (i8 < (long long)N_NODES * F_NODE / 8) {
            const float4* ip = (const float4*)(x + i8 * 8);
            float4 a = ip[0], b = ip[1];
            uint4 u;
            u.x = (uint_t)f2bf(a.x) | ((uint_t)f2bf(a.y) << 16);
            u.y = (uint_t)f2bf(a.z) | ((uint_t)f2bf(a.w) << 16);
            u.z = (uint_t)f2bf(b.x) | ((uint_t)f2bf(b.y) << 16);
            u.w = (uint_t)f2bf(b.z) | ((uint_t)f2bf(b.w) << 16);
            *reinterpret_cast<uint4*>(xbf + i8 * 8) = u;
        }
    }
}

// ---------------- CSR build ----------------
__global__ __launch_bounds__(256) void hist_k(const int* __restrict__ dst, int* __restrict__ deg)
{
    int e = blockIdx.x * 256 + threadIdx.x;
    if (e < N_EDGES) atomicAdd(&deg[dst[e]], 1);
}

__global__ __launch_bounds__(256) void scan_blocks_k(
    const int* __restrict__ deg, int* __restrict__ incl, int* __restrict__ bsum)
{
    __shared__ int sh[256];
    int i = blockIdx.x * 256 + threadIdx.x;
    int v = (i < N_NODES) ? deg[i] : 0;
    sh[threadIdx.x] = v;
    __syncthreads();
    #pragma unroll
    for (int off = 1; off < 256; off <<= 1) {
        int t = (threadIdx.x >= off) ? sh[threadIdx.x - off] : 0;
        __syncthreads();
        sh[threadIdx.x] += t;
        __syncthreads();
    }
    if (i < N_NODES) incl[i] = sh[threadIdx.x];
    if (threadIdx.x == 255) bsum[blockIdx.x] = sh[255];
}

__global__ __launch_bounds__(256) void scan_bsum_k(int* __restrict__ bsum, int nb)
{
    __shared__ int sh[256];
    int run = 0;
    for (int base = 0; base < nb; base += 256) {
        int i = base + threadIdx.x;
        int v = (i < nb) ? bsum[i] : 0;
        sh[threadIdx.x] = v;
        __syncthreads();
        #pragma unroll
        for (int off = 1; off < 256; off <<= 1) {
            int t = (threadIdx.x >= off) ? sh[threadIdx.x - off] : 0;
            __syncthreads();
            sh[threadIdx.x] += t;
            __syncthreads();
        }
        if (i < nb) bsum[i] = run + sh[threadIdx.x] - v;  // exclusive
        run += sh[255];
        __syncthreads();
    }
}

__global__ __launch_bounds__(256) void finalize_csr_k(
    const int* __restrict__ deg, const int* __restrict__ incl,
    const int* __restrict__ bsum, int* __restrict__ rowptr, int* __restrict__ cursor)
{
    int i = blockIdx.x * 256 + threadIdx.x;
    if (i >= N_NODES) return;
    int v = incl[i] + bsum[blockIdx.x];
    rowptr[i + 1] = v;
    cursor[i] = v - deg[i];
    if (i == 0) rowptr[0] = 0;
}

__global__ __launch_bounds__(256) void fill_edges_k(
    const int* __restrict__ src, const int* __restrict__ dst,
    int* __restrict__ cursor, int* __restrict__ col)
{
    int e = blockIdx.x * 256 + threadIdx.x;
    if (e >= N_EDGES) return;
    int pos = atomicAdd(&cursor[dst[e]], 1);
    col[pos] = src[e];
}

// ---------------- fused GIN layer ----------------
// ROWS rows/block; 256/ROWS threads per row, each owning K/(256/ROWS) features.
// Serial per-row gather (round-5 proven). B-fragments streamed per-ks (low VGPR).
template<int K, int ROWS, bool POOL>
__global__ __launch_bounds__(256, 6) void fused_layer_k(
    const ushort_t* __restrict__ xin, const int* __restrict__ rowptr,
    const int* __restrict__ col, const ushort_t* __restrict__ wp1,
    const float* __restrict__ b1, const float* __restrict__ gamma,
    const float* __restrict__ beta, const float* __restrict__ rmean,
    const float* __restrict__ rvar, const ushort_t* __restrict__ wp2,
    const float* __restrict__ b2, ushort_t* __restrict__ out,
    const int* __restrict__ batch, float* __restrict__ pooled)
{
    constexpr int KS1 = K / 32;
    constexpr int KS2 = 4;             // GEMM2 K = 128
    constexpr int LDA = K + 8;
    constexpr int LDT = HDIM + 8;      // 136
    constexpr int TPR = 256 / ROWS;    // threads per row
    constexpr int FPT = K / TPR;       // features per thread
    constexpr int NV  = FPT / 8;       // uint4 per edge per thread
    constexpr int MT  = ROWS / 32;     // M-tiles per wave (wm splits ROWS/2)
    __shared__ ushort_t A_lds[ROWS * LDT];
    __shared__ int batch_l[ROWS];

    const int tid  = threadIdx.x;
    const int lane = tid & 63;
    const int wid  = tid >> 6;
    const int wm   = wid >> 1;
    const int wn   = wid & 1;
    const long long m0 = (long long)blockIdx.x * ROWS;

    if (POOL && tid < ROWS) batch_l[tid] = batch[m0 + tid];

    // ---- gather-stage: TPR threads/row, FPT features each, f32 accumulate ----
    {
        const int row = tid / TPR;
        const int fq  = (tid % TPR) * FPT;
        long long n = m0 + row;
        float acc[FPT];
        {
            const uint4* xp = (const uint4*)(xin + n * (long long)K + fq);
            #pragma unroll
            for (int v = 0; v < NV; ++v) {
                uint4 u = xp[v];
                acc[v*8+0]=bf2f(u.x&0xffff); acc[v*8+1]=bf2f(u.x>>16);
                acc[v*8+2]=bf2f(u.y&0xffff); acc[v*8+3]=bf2f(u.y>>16);
                acc[v*8+4]=bf2f(u.z&0xffff); acc[v*8+5]=bf2f(u.z>>16);
                acc[v*8+6]=bf2f(u.w&0xffff); acc[v*8+7]=bf2f(u.w>>16);
            }
        }
        const int p0 = rowptr[n], p1 = rowptr[n + 1];
        for (int p = p0; p < p1; ++p) {
            long long s = col[p];
            const uint4* sp = (const uint4*)(xin + s * (long long)K + fq);
            uint4 u[NV];
            #pragma unroll
            for (int v = 0; v < NV; ++v) u[v] = sp[v];
            #pragma unroll
            for (int v = 0; v < NV; ++v) {
                acc[v*8+0]+=bf2f(u[v].x&0xffff); acc[v*8+1]+=bf2f(u[v].x>>16);
                acc[v*8+2]+=bf2f(u[v].y&0xffff); acc[v*8+3]+=bf2f(u[v].y>>16);
                acc[v*8+4]+=bf2f(u[v].z&0xffff); acc[v*8+5]+=bf2f(u[v].z>>16);
                acc[v*8+6]+=bf2f(u[v].w&0xffff); acc[v*8+7]+=bf2f(u[v].w>>16);
            }
        }
        #pragma unroll
        for (int f = 0; f < FPT; f += 2) {
            uint_t pk = (uint_t)f2bf(acc[f]) | ((uint_t)f2bf(acc[f+1]) << 16);
            *reinterpret_cast<uint_t*>(&A_lds[row * LDA + fq + f]) = pk;
        }
    }
    __syncthreads();

    // ---- GEMM1 K-loop (B-fragments streamed per-ks) ----
    f32x4 acc1[MT][4] = {};
    #pragma unroll 1
    for (int ks = 0; ks < KS1; ++ks) {
        short8 bfrag[4];
        #pragma unroll
        for (int nt = 0; nt < 4; ++nt)
            bfrag[nt] = *reinterpret_cast<const short8*>(
                wp1 + (((((wn * 4 + nt) * KS1) + ks) * 64 + lane) << 3));
        short8 afrag[MT];
        #pragma unroll
        for (int mt = 0; mt < MT; ++mt) {
            int row = (wm * MT + mt) * 16 + (lane & 15);
            int c   = ks * 32 + ((lane >> 4) << 3);
            afrag[mt] = *reinterpret_cast<const short8*>(&A_lds[row * LDA + c]);
        }
        #pragma unroll
        for (int mt = 0; mt < MT; ++mt)
            #pragma unroll
            for (int nt = 0; nt < 4; ++nt)
                acc1[mt][nt] = __builtin_amdgcn_mfma_f32_16x16x32_bf16(
                    afrag[mt], bfrag[nt], acc1[mt][nt], 0, 0, 0);
    }
    __syncthreads();   // all waves done reading A_lds

    // ---- BN + ReLU -> T into A_lds (LDT layout) ----
    #pragma unroll
    for (int nt = 0; nt < 4; ++nt) {
        int c = wn * 64 + nt * 16 + (lane & 15);
        float rs = rsqrtf(rvar[c] + BN_EPS);
        float scale = gamma[c] * rs;
        float shift = (b1[c] - rmean[c]) * scale + beta[c];
        #pragma unroll
        for (int mt = 0; mt < MT; ++mt) {
            int rowb = (wm * MT + mt) * 16 + ((lane >> 4) << 2);
            #pragma unroll
            for (int r = 0; r < 4; ++r) {
                float v = fmaxf(acc1[mt][nt][r] * scale + shift, 0.f);
                A_lds[(rowb + r) * LDT + c] = f2bf(v);
            }
        }
    }
    __syncthreads();

    // ---- GEMM2 K-loop (K = 128 over T, streamed B) ----
    f32x4 acc2[MT][4] = {};
    #pragma unroll 1
    for (int ks = 0; ks < KS2; ++ks) {
        short8 bfrag[4];
        #pragma unroll
        for (int nt = 0; nt < 4; ++nt)
            bfrag[nt] = *reinterpret_cast<const short8*>(
                wp2 + (((((wn * 4 + nt) * KS2) + ks) * 64 + lane) << 3));
        short8 afrag[MT];
        #pragma unroll
        for (int mt = 0; mt < MT; ++mt) {
            int row = (wm * MT + mt) * 16 + (lane & 15);
            int c   = ks * 32 + ((lane >> 4) << 3);
            afrag[mt] = *reinterpret_cast<const short8*>(&A_lds[row * LDT + c]);
        }
        #pragma unroll
        for (int mt = 0; mt < MT; ++mt)
            #pragma unroll
            for (int nt = 0; nt < 4; ++nt)
                acc2[mt][nt] = __builtin_amdgcn_mfma_f32_16x16x32_bf16(
                    afrag[mt], bfrag[nt], acc2[mt][nt], 0, 0, 0);
    }

    if (!POOL) {
        #pragma unroll
        for (int nt = 0; nt < 4; ++nt) {
            int c = wn * 64 + nt * 16 + (lane & 15);
            float bias = b2[c];
            #pragma unroll
            for (int mt = 0; mt < MT; ++mt) {
                long long rowb = m0 + (wm * MT + mt) * 16 + ((lane >> 4) << 2);
                #pragma unroll
                for (int r = 0; r < 4; ++r) {
                    float v = fmaxf(acc2[mt][nt][r] + bias, 0.f);
                    out[(rowb + r) * HDIM + c] = f2bf(v);
                }
            }
        }
    } else {
        __syncthreads();   // all waves done reading T
        #pragma unroll
        for (int nt = 0; nt < 4; ++nt) {
            int c = wn * 64 + nt * 16 + (lane & 15);
            float bias = b2[c];
            #pragma unroll
            for (int mt = 0; mt < MT; ++mt) {
                int rowb = (wm * MT + mt) * 16 + ((lane >> 4) << 2);
                #pragma unroll
                for (int r = 0; r < 4; ++r) {
                    float v = fmaxf(acc2[mt][nt][r] + bias, 0.f);
                    A_lds[(rowb + r) * LDT + c] = f2bf(v);
                }
            }
        }
        __syncthreads();
        if (tid < HDIM) {
            int colw = tid;
            int curb = batch_l[0];
            float s = 0.f;
            #pragma unroll 8
            for (int r = 0; r < ROWS; ++r) {
                int b = batch_l[r];
                if (b != curb) {
                    atomicAdd(&pooled[(long long)curb * HDIM + colw], s);
                    curb = b; s = 0.f;
                }
                s += bf2f(A_lds[r * LDT + colw]);
            }
            atomicAdd(&pooled[(long long)curb * HDIM + colw], s);
        }
    }
}

// ---------------- head ----------------
__global__ __launch_bounds__(64) void fc_head_k(
    const float* __restrict__ pooled,
    const float* __restrict__ w_fc1, const float* __restrict__ b_fc1,
    const float* __restrict__ w_fc2, const float* __restrict__ b_fc2,
    float* __restrict__ out)
{
    int g = blockIdx.x;
    int j = threadIdx.x;   // 0..63
    __shared__ float p[HDIM];
    p[j]      = pooled[(long long)g * HDIM + j];
    p[j + 64] = pooled[(long long)g * HDIM + j + 64];
    __syncthreads();

    float acc = b_fc1[j];
    #pragma unroll 8
    for (int k = 0; k < HDIM; ++k) acc += p[k] * w_fc1[k * 64 + j];
    acc = fmaxf(acc, 0.f);

    float v = acc * w_fc2[j];
    #pragma unroll
    for (int off = 32; off > 0; off >>= 1) v += __shfl_down(v, off, 64);
    if (j == 0) out[g] = v + b_fc2[0];
}

extern "C" void kernel_launch(void* const* d_in, const int* in_sizes, int n_in,
                              void* d_out, int out_size, void* d_ws, size_t ws_size,
                              hipStream_t stream) {
    const float* x     = (const float*)d_in[0];
    const int*   ei    = (const int*)d_in[1];
    const int*   src   = ei;                // edge_index[0]
    const int*   dst   = ei + N_EDGES;      // edge_index[1]
    const int*   batch = (const int*)d_in[3];
    const float* L[3][8];
    for (int l = 0; l < 3; ++l)
        for (int p = 0; p < 8; ++p)
            L[l][p] = (const float*)d_in[4 + 8 * l + p];
    const float* w_fc1 = (const float*)d_in[30];
    const float* b_fc1 = (const float*)d_in[31];
    const float* w_fc2 = (const float*)d_in[32];
    const float* b_fc2 = (const float*)d_in[33];
    float* out = (float*)d_out;

    // ---- workspace layout (bytes); pooled|deg contiguous for single zero-fill ----
    char* base = (char*)d_ws;
    ushort_t* hA     = (ushort_t*)(base);                 // bf16 [N,128] 51.2 MB
    ushort_t* hB     = (ushort_t*)(base + 51200000);      // bf16 [N,128] 51.2 MB
    ushort_t* xbf    = (ushort_t*)(base + 102400000);     // bf16 [N,32] 12.8 MB
    float*    pooled = (float*)   (base + 115200000);     // f32 [G,128] 5.12 MB
    int*      deg    = (int*)     (base + 120320000);     // 800 KB (after pooled)
    int*      incl   = (int*)     (base + 121120000);     // 800 KB
    int*      bsum   = (int*)     (base + 121920000);     // 4 KB
    int*      rowptr = (int*)     (base + 121924096);     // 800,004 B
    int*      cursor = (int*)     (base + 122724112);     // 800 KB
    int*      colarr = (int*)     (base + 123524112);     // 2.4 MB
    ushort_t* wp     = (ushort_t*)(base + 125924112);     // 172 KB

    ushort_t* wp1_1 = wp;
    ushort_t* wp2_1 = wp + 4096;
    ushort_t* wp1_2 = wp + 20480;
    ushort_t* wp2_2 = wp + 36864;
    ushort_t* wp1_3 = wp + 53248;
    ushort_t* wp2_3 = wp + 69632;

    const int NB_NODE = (N_NODES + 255) / 256; // 782
    const int NB_EDGE = (N_EDGES + 255) / 256; // 2344

    // ---- single zero-fill: pooled (1.28M f32) + deg (200k int), contiguous ----
    fill_zero_k<<<512, 256, 0, stream>>>((uint_t*)pooled,
        (long long)N_GRAPHS * HDIM + N_NODES);

    // ---- prep: all weight permutes + x->bf16 in one kernel ----
    {
        long long tot = 86016 + (long long)N_NODES * F_NODE / 8;
        prep_k<<<(int)((tot + 255) / 256), 256, 0, stream>>>(
            L[0][0], L[0][6], L[1][0], L[1][6], L[2][0], L[2][6], wp, x, xbf);
    }

    // ---- CSR build ----
    hist_k<<<NB_EDGE, 256, 0, stream>>>(dst, deg);
    scan_blocks_k<<<NB_NODE, 256, 0, stream>>>(deg, incl, bsum);
    scan_bsum_k<<<1, 256, 0, stream>>>(bsum, NB_NODE);
    finalize_csr_k<<<NB_NODE, 256, 0, stream>>>(deg, incl, bsum, rowptr, cursor);
    fill_edges_k<<<NB_EDGE, 256, 0, stream>>>(src, dst, cursor, colarr);

    // ---- 3 fused layers ----
    fused_layer_k<F_NODE, 64, false><<<N_NODES / 64, 256, 0, stream>>>(
        xbf, rowptr, colarr, wp1_1, L[0][1], L[0][2], L[0][3], L[0][4], L[0][5],
        wp2_1, L[0][7], hA, nullptr, nullptr);
    fused_layer_k<HDIM, 32, false><<<N_NODES / 32, 256, 0, stream>>>(
        hA, rowptr, colarr, wp1_2, L[1][1], L[1][2], L[1][3], L[1][4], L[1][5],
        wp2_2, L[1][7], hB, nullptr, nullptr);
    fused_layer_k<HDIM, 32, true><<<N_NODES / 32, 256, 0, stream>>>(
        hB, rowptr, colarr, wp1_3, L[2][1], L[2][2], L[2][3], L[2][4], L[2][5],
        wp2_3, L[2][7], nullptr, batch, pooled);

    // ---- head ----
    fc_head_k<<<N_GRAPHS, 64, 0, stream>>>(pooled, w_fc1, b_fc1, w_fc2, b_fc2, out);
}

// Round 10
// 248.950 us; speedup vs baseline: 1.2147x; 1.0242x over previous
//
#include <hip/hip_runtime.h>

#define N_NODES 200000
#define N_EDGES 600000
#define N_GRAPHS 10000
#define F_NODE 32
#define HDIM 128
#define BN_EPS 1e-5f

typedef unsigned short ushort_t;
typedef unsigned int uint_t;
typedef __attribute__((ext_vector_type(8))) short short8;
typedef __attribute__((ext_vector_type(4))) float f32x4;

__device__ __forceinline__ ushort_t f2bf(float f) {
    uint_t u = __builtin_bit_cast(uint_t, f);
    u += 0x7FFFu + ((u >> 16) & 1u);   // RNE
    return (ushort_t)(u >> 16);
}
__device__ __forceinline__ float bf2f(ushort_t h) {
    uint_t u = ((uint_t)h) << 16;
    return __builtin_bit_cast(float, u);
}

// ---------------- prep: zeros (pooled+deg) + 6 weight permutes + x->bf16 ----------------
// ranges (in 256-thread grid-linear ids):
//   [0, 86016)                 weight permute
//   [86016, 86016+100000)      xbf convert (8 elems each)
//   then zero range: pooled 1.28M f32 + deg 200k int = 1.48M words (4 each)
#define PREP_W   86016
#define PREP_X   (PREP_W + N_NODES * F_NODE / 8)                 // 886016... (100000)
#define PREP_Z   (PREP_X + (N_GRAPHS * HDIM + N_NODES + 3) / 4)  // + 370000
__global__ __launch_bounds__(256) void prep_k(
    const float* __restrict__ w1_1, const float* __restrict__ w2_1,
    const float* __restrict__ w1_2, const float* __restrict__ w2_2,
    const float* __restrict__ w1_3, const float* __restrict__ w2_3,
    ushort_t* __restrict__ wp, const float* __restrict__ x, ushort_t* __restrict__ xbf,
    uint_t* __restrict__ zbase)
{
    int gid = blockIdx.x * 256 + threadIdx.x;
    if (gid < PREP_W) {
        const float* w; int lidx; int K;
        if (gid < 4096)       { w = w1_1; lidx = gid;         K = 32; }
        else if (gid < 20480) { w = w2_1; lidx = gid - 4096;  K = 128; }
        else if (gid < 36864) { w = w1_2; lidx = gid - 20480; K = 128; }
        else if (gid < 53248) { w = w2_2; lidx = gid - 36864; K = 128; }
        else if (gid < 69632) { w = w1_3; lidx = gid - 53248; K = 128; }
        else                  { w = w2_3; lidx = gid - 69632; K = 128; }
        int KS = K / 32;
        int idx = lidx;
        int j = idx & 7; idx >>= 3;
        int lane = idx & 63; idx >>= 6;
        int ks = idx % KS;
        int ntg = idx / KS;
        int k = ks * 32 + ((lane >> 4) << 3) + j;
        int n = ntg * 16 + (lane & 15);
        wp[gid] = f2bf(w[k * HDIM + n]);
    } else if (gid < PREP_X) {
        long long i8 = gid - PREP_W;
        const float4* ip = (const float4*)(x + i8 * 8);
        float4 a = ip[0], b = ip[1];
        uint4 u;
        u.x = (uint_t)f2bf(a.x) | ((uint_t)f2bf(a.y) << 16);
        u.y = (uint_t)f2bf(a.z) | ((uint_t)f2bf(a.w) << 16);
        u.z = (uint_t)f2bf(b.x) | ((uint_t)f2bf(b.y) << 16);
        u.w = (uint_t)f2bf(b.z) | ((uint_t)f2bf(b.w) << 16);
        *reinterpret_cast<uint4*>(xbf + i8 * 8) = u;
    } else if (gid < PREP_Z) {
        long long i4 = gid - PREP_X;
        long long total = (long long)N_GRAPHS * HDIM + N_NODES;
        long long o = i4 * 4;
        if (o + 4 <= total) {
            uint4 z = {0u, 0u, 0u, 0u};
            *reinterpret_cast<uint4*>(zbase + o) = z;
        } else {
            for (long long k = o; k < total; ++k) zbase[k] = 0u;
        }
    }
}

// ---------------- CSR build ----------------
__global__ __launch_bounds__(256) void hist_k(const int* __restrict__ dst, int* __restrict__ deg)
{
    int e = blockIdx.x * 256 + threadIdx.x;
    if (e < N_EDGES) atomicAdd(&deg[dst[e]], 1);
}

__global__ __launch_bounds__(256) void scan_blocks_k(
    const int* __restrict__ deg, int* __restrict__ incl, int* __restrict__ bsum)
{
    __shared__ int sh[256];
    int i = blockIdx.x * 256 + threadIdx.x;
    int v = (i < N_NODES) ? deg[i] : 0;
    sh[threadIdx.x] = v;
    __syncthreads();
    #pragma unroll
    for (int off = 1; off < 256; off <<= 1) {
        int t = (threadIdx.x >= off) ? sh[threadIdx.x - off] : 0;
        __syncthreads();
        sh[threadIdx.x] += t;
        __syncthreads();
    }
    if (i < N_NODES) incl[i] = sh[threadIdx.x];
    if (threadIdx.x == 255) bsum[blockIdx.x] = sh[255];
}

__global__ __launch_bounds__(256) void scan_bsum_k(int* __restrict__ bsum, int nb)
{
    __shared__ int sh[256];
    int run = 0;
    for (int base = 0; base < nb; base += 256) {
        int i = base + threadIdx.x;
        int v = (i < nb) ? bsum[i] : 0;
        sh[threadIdx.x] = v;
        __syncthreads();
        #pragma unroll
        for (int off = 1; off < 256; off <<= 1) {
            int t = (threadIdx.x >= off) ? sh[threadIdx.x - off] : 0;
            __syncthreads();
            sh[threadIdx.x] += t;
            __syncthreads();
        }
        if (i < nb) bsum[i] = run + sh[threadIdx.x] - v;  // exclusive
        run += sh[255];
        __syncthreads();
    }
}

__global__ __launch_bounds__(256) void finalize_csr_k(
    const int* __restrict__ deg, const int* __restrict__ incl,
    const int* __restrict__ bsum, int* __restrict__ rowptr, int* __restrict__ cursor)
{
    int i = blockIdx.x * 256 + threadIdx.x;
    if (i >= N_NODES) return;
    int v = incl[i] + bsum[blockIdx.x];
    rowptr[i + 1] = v;
    cursor[i] = v - deg[i];
    if (i == 0) rowptr[0] = 0;
}

__global__ __launch_bounds__(256) void fill_edges_k(
    const int* __restrict__ src, const int* __restrict__ dst,
    int* __restrict__ cursor, int* __restrict__ col)
{
    int e = blockIdx.x * 256 + threadIdx.x;
    if (e >= N_EDGES) return;
    int pos = atomicAdd(&cursor[dst[e]], 1);
    col[pos] = src[e];
}

// ---------------- fused GIN layer ----------------
// ROWS rows/block; TPR=256/ROWS threads/row, FPT=K/TPR features each.
// Gather edge loop software-pipelined 2-deep (issue p+1 loads before accumulating p).
template<int K, int ROWS, bool POOL>
__global__ __launch_bounds__(256, 6) void fused_layer_k(
    const ushort_t* __restrict__ xin, const int* __restrict__ rowptr,
    const int* __restrict__ col, const ushort_t* __restrict__ wp1,
    const float* __restrict__ b1, const float* __restrict__ gamma,
    const float* __restrict__ beta, const float* __restrict__ rmean,
    const float* __restrict__ rvar, const ushort_t* __restrict__ wp2,
    const float* __restrict__ b2, ushort_t* __restrict__ out,
    const int* __restrict__ batch, float* __restrict__ pooled)
{
    constexpr int KS1 = K / 32;
    constexpr int KS2 = 4;
    constexpr int LDA = K + 8;
    constexpr int LDT = HDIM + 8;
    constexpr int TPR = 256 / ROWS;
    constexpr int FPT = K / TPR;
    constexpr int NV  = FPT / 8;
    constexpr int MT  = ROWS / 32;
    __shared__ ushort_t A_lds[ROWS * LDT];
    __shared__ int batch_l[ROWS];

    const int tid  = threadIdx.x;
    const int lane = tid & 63;
    const int wid  = tid >> 6;
    const int wm   = wid >> 1;
    const int wn   = wid & 1;
    const long long m0 = (long long)blockIdx.x * ROWS;

    if (POOL && tid < ROWS) batch_l[tid] = batch[m0 + tid];

    // ---- gather-stage: TPR threads/row, 2-deep pipelined edge loop ----
    {
        const int row = tid / TPR;
        const int fq  = (tid % TPR) * FPT;
        long long n = m0 + row;
        float acc[FPT];
        {
            const uint4* xp = (const uint4*)(xin + n * (long long)K + fq);
            #pragma unroll
            for (int v = 0; v < NV; ++v) {
                uint4 u = xp[v];
                acc[v*8+0]=bf2f(u.x&0xffff); acc[v*8+1]=bf2f(u.x>>16);
                acc[v*8+2]=bf2f(u.y&0xffff); acc[v*8+3]=bf2f(u.y>>16);
                acc[v*8+4]=bf2f(u.z&0xffff); acc[v*8+5]=bf2f(u.z>>16);
                acc[v*8+6]=bf2f(u.w&0xffff); acc[v*8+7]=bf2f(u.w>>16);
            }
        }
        const int p0 = rowptr[n], p1 = rowptr[n + 1];
        if (p0 < p1) {
            uint4 cur[NV];
            {
                long long s = col[p0];
                const uint4* sp = (const uint4*)(xin + s * (long long)K + fq);
                #pragma unroll
                for (int v = 0; v < NV; ++v) cur[v] = sp[v];
            }
            for (int p = p0 + 1; p < p1; ++p) {
                long long s = col[p];
                const uint4* sp = (const uint4*)(xin + s * (long long)K + fq);
                uint4 nxt[NV];
                #pragma unroll
                for (int v = 0; v < NV; ++v) nxt[v] = sp[v];   // in flight during accumulate
                #pragma unroll
                for (int v = 0; v < NV; ++v) {
                    acc[v*8+0]+=bf2f(cur[v].x&0xffff); acc[v*8+1]+=bf2f(cur[v].x>>16);
                    acc[v*8+2]+=bf2f(cur[v].y&0xffff); acc[v*8+3]+=bf2f(cur[v].y>>16);
                    acc[v*8+4]+=bf2f(cur[v].z&0xffff); acc[v*8+5]+=bf2f(cur[v].z>>16);
                    acc[v*8+6]+=bf2f(cur[v].w&0xffff); acc[v*8+7]+=bf2f(cur[v].w>>16);
                }
                #pragma unroll
                for (int v = 0; v < NV; ++v) cur[v] = nxt[v];
            }
            #pragma unroll
            for (int v = 0; v < NV; ++v) {
                acc[v*8+0]+=bf2f(cur[v].x&0xffff); acc[v*8+1]+=bf2f(cur[v].x>>16);
                acc[v*8+2]+=bf2f(cur[v].y&0xffff); acc[v*8+3]+=bf2f(cur[v].y>>16);
                acc[v*8+4]+=bf2f(cur[v].z&0xffff); acc[v*8+5]+=bf2f(cur[v].z>>16);
                acc[v*8+6]+=bf2f(cur[v].w&0xffff); acc[v*8+7]+=bf2f(cur[v].w>>16);
            }
        }
        #pragma unroll
        for (int f = 0; f < FPT; f += 2) {
            uint_t pk = (uint_t)f2bf(acc[f]) | ((uint_t)f2bf(acc[f+1]) << 16);
            *reinterpret_cast<uint_t*>(&A_lds[row * LDA + fq + f]) = pk;
        }
    }
    __syncthreads();

    // ---- GEMM1 K-loop (B streamed per-ks) ----
    f32x4 acc1[MT][4] = {};
    #pragma unroll 1
    for (int ks = 0; ks < KS1; ++ks) {
        short8 bfrag[4];
        #pragma unroll
        for (int nt = 0; nt < 4; ++nt)
            bfrag[nt] = *reinterpret_cast<const short8*>(
                wp1 + (((((wn * 4 + nt) * KS1) + ks) * 64 + lane) << 3));
        short8 afrag[MT];
        #pragma unroll
        for (int mt = 0; mt < MT; ++mt) {
            int row = (wm * MT + mt) * 16 + (lane & 15);
            int c   = ks * 32 + ((lane >> 4) << 3);
            afrag[mt] = *reinterpret_cast<const short8*>(&A_lds[row * LDA + c]);
        }
        #pragma unroll
        for (int mt = 0; mt < MT; ++mt)
            #pragma unroll
            for (int nt = 0; nt < 4; ++nt)
                acc1[mt][nt] = __builtin_amdgcn_mfma_f32_16x16x32_bf16(
                    afrag[mt], bfrag[nt], acc1[mt][nt], 0, 0, 0);
    }
    __syncthreads();

    // ---- BN + ReLU -> T ----
    #pragma unroll
    for (int nt = 0; nt < 4; ++nt) {
        int c = wn * 64 + nt * 16 + (lane & 15);
        float rs = rsqrtf(rvar[c] + BN_EPS);
        float scale = gamma[c] * rs;
        float shift = (b1[c] - rmean[c]) * scale + beta[c];
        #pragma unroll
        for (int mt = 0; mt < MT; ++mt) {
            int rowb = (wm * MT + mt) * 16 + ((lane >> 4) << 2);
            #pragma unroll
            for (int r = 0; r < 4; ++r) {
                float v = fmaxf(acc1[mt][nt][r] * scale + shift, 0.f);
                A_lds[(rowb + r) * LDT + c] = f2bf(v);
            }
        }
    }
    __syncthreads();

    // ---- GEMM2 K-loop ----
    f32x4 acc2[MT][4] = {};
    #pragma unroll 1
    for (int ks = 0; ks < KS2; ++ks) {
        short8 bfrag[4];
        #pragma unroll
        for (int nt = 0; nt < 4; ++nt)
            bfrag[nt] = *reinterpret_cast<const short8*>(
                wp2 + (((((wn * 4 + nt) * KS2) + ks) * 64 + lane) << 3));
        short8 afrag[MT];
        #pragma unroll
        for (int mt = 0; mt < MT; ++mt) {
            int row = (wm * MT + mt) * 16 + (lane & 15);
            int c   = ks * 32 + ((lane >> 4) << 3);
            afrag[mt] = *reinterpret_cast<const short8*>(&A_lds[row * LDT + c]);
        }
        #pragma unroll
        for (int mt = 0; mt < MT; ++mt)
            #pragma unroll
            for (int nt = 0; nt < 4; ++nt)
                acc2[mt][nt] = __builtin_amdgcn_mfma_f32_16x16x32_bf16(
                    afrag[mt], bfrag[nt], acc2[mt][nt], 0, 0, 0);
    }

    if (!POOL) {
        #pragma unroll
        for (int nt = 0; nt < 4; ++nt) {
            int c = wn * 64 + nt * 16 + (lane & 15);
            float bias = b2[c];
            #pragma unroll
            for (int mt = 0; mt < MT; ++mt) {
                long long rowb = m0 + (wm * MT + mt) * 16 + ((lane >> 4) << 2);
                #pragma unroll
                for (int r = 0; r < 4; ++r) {
                    float v = fmaxf(acc2[mt][nt][r] + bias, 0.f);
                    out[(rowb + r) * HDIM + c] = f2bf(v);
                }
            }
        }
    } else {
        __syncthreads();
        #pragma unroll
        for (int nt = 0; nt < 4; ++nt) {
            int c = wn * 64 + nt * 16 + (lane & 15);
            float bias = b2[c];
            #pragma unroll
            for (int mt = 0; mt < MT; ++mt) {
                int rowb = (wm * MT + mt) * 16 + ((lane >> 4) << 2);
                #pragma unroll
                for (int r = 0; r < 4; ++r) {
                    float v = fmaxf(acc2[mt][nt][r] + bias, 0.f);
                    A_lds[(rowb + r) * LDT + c] = f2bf(v);
                }
            }
        }
        __syncthreads();
        if (tid < HDIM) {
            int colw = tid;
            int curb = batch_l[0];
            float s = 0.f;
            #pragma unroll 8
            for (int r = 0; r < ROWS; ++r) {
                int b = batch_l[r];
                if (b != curb) {
                    atomicAdd(&pooled[(long long)curb * HDIM + colw], s);
                    curb = b; s = 0.f;
                }
                s += bf2f(A_lds[r * LDT + colw]);
            }
            atomicAdd(&pooled[(long long)curb * HDIM + colw], s);
        }
    }
}

// ---------------- head ----------------
__global__ __launch_bounds__(64) void fc_head_k(
    const float* __restrict__ pooled,
    const float* __restrict__ w_fc1, const float* __restrict__ b_fc1,
    const float* __restrict__ w_fc2, const float* __restrict__ b_fc2,
    float* __restrict__ out)
{
    int g = blockIdx.x;
    int j = threadIdx.x;   // 0..63
    __shared__ float p[HDIM];
    p[j]      = pooled[(long long)g * HDIM + j];
    p[j + 64] = pooled[(long long)g * HDIM + j + 64];
    __syncthreads();

    float acc = b_fc1[j];
    #pragma unroll 8
    for (int k = 0; k < HDIM; ++k) acc += p[k] * w_fc1[k * 64 + j];
    acc = fmaxf(acc, 0.f);

    float v = acc * w_fc2[j];
    #pragma unroll
    for (int off = 32; off > 0; off >>= 1) v += __shfl_down(v, off, 64);
    if (j == 0) out[g] = v + b_fc2[0];
}

extern "C" void kernel_launch(void* const* d_in, const int* in_sizes, int n_in,
                              void* d_out, int out_size, void* d_ws, size_t ws_size,
                              hipStream_t stream) {
    const float* x     = (const float*)d_in[0];
    const int*   ei    = (const int*)d_in[1];
    const int*   src   = ei;                // edge_index[0]
    const int*   dst   = ei + N_EDGES;      // edge_index[1]
    const int*   batch = (const int*)d_in[3];
    const float* L[3][8];
    for (int l = 0; l < 3; ++l)
        for (int p = 0; p < 8; ++p)
            L[l][p] = (const float*)d_in[4 + 8 * l + p];
    const float* w_fc1 = (const float*)d_in[30];
    const float* b_fc1 = (const float*)d_in[31];
    const float* w_fc2 = (const float*)d_in[32];
    const float* b_fc2 = (const float*)d_in[33];
    float* out = (float*)d_out;

    // ---- workspace layout (bytes); pooled|deg contiguous (zeroed in prep) ----
    char* base = (char*)d_ws;
    ushort_t* hA     = (ushort_t*)(base);                 // bf16 [N,128] 51.2 MB
    ushort_t* hB     = (ushort_t*)(base + 51200000);      // bf16 [N,128] 51.2 MB
    ushort_t* xbf    = (ushort_t*)(base + 102400000);     // bf16 [N,32] 12.8 MB
    float*    pooled = (float*)   (base + 115200000);     // f32 [G,128] 5.12 MB
    int*      deg    = (int*)     (base + 120320000);     // 800 KB (after pooled)
    int*      incl   = (int*)     (base + 121120000);     // 800 KB
    int*      bsum   = (int*)     (base + 121920000);     // 4 KB
    int*      rowptr = (int*)     (base + 121924096);     // 800,004 B
    int*      cursor = (int*)     (base + 122724112);     // 800 KB
    int*      colarr = (int*)     (base + 123524112);     // 2.4 MB
    ushort_t* wp     = (ushort_t*)(base + 125924112);     // 172 KB

    ushort_t* wp1_1 = wp;
    ushort_t* wp2_1 = wp + 4096;
    ushort_t* wp1_2 = wp + 20480;
    ushort_t* wp2_2 = wp + 36864;
    ushort_t* wp1_3 = wp + 53248;
    ushort_t* wp2_3 = wp + 69632;

    const int NB_NODE = (N_NODES + 255) / 256; // 782
    const int NB_EDGE = (N_EDGES + 255) / 256; // 2344

    // ---- prep: zeros + weight permutes + x->bf16 in one kernel ----
    prep_k<<<(PREP_Z + 255) / 256, 256, 0, stream>>>(
        L[0][0], L[0][6], L[1][0], L[1][6], L[2][0], L[2][6], wp, x, xbf,
        (uint_t*)pooled);

    // ---- CSR build ----
    hist_k<<<NB_EDGE, 256, 0, stream>>>(dst, deg);
    scan_blocks_k<<<NB_NODE, 256, 0, stream>>>(deg, incl, bsum);
    scan_bsum_k<<<1, 256, 0, stream>>>(bsum, NB_NODE);
    finalize_csr_k<<<NB_NODE, 256, 0, stream>>>(deg, incl, bsum, rowptr, cursor);
    fill_edges_k<<<NB_EDGE, 256, 0, stream>>>(src, dst, cursor, colarr);

    // ---- 3 fused layers ----
    fused_layer_k<F_NODE, 64, false><<<N_NODES / 64, 256, 0, stream>>>(
        xbf, rowptr, colarr, wp1_1, L[0][1], L[0][2], L[0][3], L[0][4], L[0][5],
        wp2_1, L[0][7], hA, nullptr, nullptr);
    fused_layer_k<HDIM, 32, false><<<N_NODES / 32, 256, 0, stream>>>(
        hA, rowptr, colarr, wp1_2, L[1][1], L[1][2], L[1][3], L[1][4], L[1][5],
        wp2_2, L[1][7], hB, nullptr, nullptr);
    fused_layer_k<HDIM, 32, true><<<N_NODES / 32, 256, 0, stream>>>(
        hB, rowptr, colarr, wp1_3, L[2][1], L[2][2], L[2][3], L[2][4], L[2][5],
        wp2_3, L[2][7], nullptr, batch, pooled);

    // ---- head ----
    fc_head_k<<<N_GRAPHS, 64, 0, stream>>>(pooled, w_fc1, b_fc1, w_fc2, b_fc2, out);
}

// Round 11
// 221.027 us; speedup vs baseline: 1.3682x; 1.1263x over previous
//
#include <hip/hip_runtime.h>

#define N_NODES 200000
#define N_EDGES 600000
#define N_GRAPHS 10000
#define F_NODE 32
#define HDIM 128
#define BN_EPS 1e-5f
#define BCAP 32          // bucket capacity per node; P(deg>32) ~ 1e-25 for Poisson(3)

typedef unsigned short ushort_t;
typedef unsigned int uint_t;
typedef __attribute__((ext_vector_type(8))) short short8;
typedef __attribute__((ext_vector_type(4))) float f32x4;

__device__ __forceinline__ ushort_t f2bf(float f) {
    uint_t u = __builtin_bit_cast(uint_t, f);
    u += 0x7FFFu + ((u >> 16) & 1u);   // RNE
    return (ushort_t)(u >> 16);
}
__device__ __forceinline__ float bf2f(ushort_t h) {
    uint_t u = ((uint_t)h) << 16;
    return __builtin_bit_cast(float, u);
}

// ---------------- prep: zeros (pooled+cnt) + 6 weight permutes + x->bf16 ----------------
#define PREP_W   86016
#define PREP_X   (PREP_W + N_NODES * F_NODE / 8)
#define PREP_Z   (PREP_X + (N_GRAPHS * HDIM + N_NODES + 3) / 4)
__global__ __launch_bounds__(256) void prep_k(
    const float* __restrict__ w1_1, const float* __restrict__ w2_1,
    const float* __restrict__ w1_2, const float* __restrict__ w2_2,
    const float* __restrict__ w1_3, const float* __restrict__ w2_3,
    ushort_t* __restrict__ wp, const float* __restrict__ x, ushort_t* __restrict__ xbf,
    uint_t* __restrict__ zbase)
{
    int gid = blockIdx.x * 256 + threadIdx.x;
    if (gid < PREP_W) {
        const float* w; int lidx; int K;
        if (gid < 4096)       { w = w1_1; lidx = gid;         K = 32; }
        else if (gid < 20480) { w = w2_1; lidx = gid - 4096;  K = 128; }
        else if (gid < 36864) { w = w1_2; lidx = gid - 20480; K = 128; }
        else if (gid < 53248) { w = w2_2; lidx = gid - 36864; K = 128; }
        else if (gid < 69632) { w = w1_3; lidx = gid - 53248; K = 128; }
        else                  { w = w2_3; lidx = gid - 69632; K = 128; }
        int KS = K / 32;
        int idx = lidx;
        int j = idx & 7; idx >>= 3;
        int lane = idx & 63; idx >>= 6;
        int ks = idx % KS;
        int ntg = idx / KS;
        int k = ks * 32 + ((lane >> 4) << 3) + j;
        int n = ntg * 16 + (lane & 15);
        wp[gid] = f2bf(w[k * HDIM + n]);
    } else if (gid < PREP_X) {
        long long i8 = gid - PREP_W;
        const float4* ip = (const float4*)(x + i8 * 8);
        float4 a = ip[0], b = ip[1];
        uint4 u;
        u.x = (uint_t)f2bf(a.x) | ((uint_t)f2bf(a.y) << 16);
        u.y = (uint_t)f2bf(a.z) | ((uint_t)f2bf(a.w) << 16);
        u.z = (uint_t)f2bf(b.x) | ((uint_t)f2bf(b.y) << 16);
        u.w = (uint_t)f2bf(b.z) | ((uint_t)f2bf(b.w) << 16);
        *reinterpret_cast<uint4*>(xbf + i8 * 8) = u;
    } else if (gid < PREP_Z) {
        long long i4 = gid - PREP_X;
        long long total = (long long)N_GRAPHS * HDIM + N_NODES;
        long long o = i4 * 4;
        if (o + 4 <= total) {
            uint4 z = {0u, 0u, 0u, 0u};
            *reinterpret_cast<uint4*>(zbase + o) = z;
        } else {
            for (long long k = o; k < total; ++k) zbase[k] = 0u;
        }
    }
}

// ---------------- one-kernel adjacency build: fixed-capacity buckets ----------------
__global__ __launch_bounds__(256) void fill_bucket_k(
    const int* __restrict__ src, const int* __restrict__ dst,
    int* __restrict__ cnt, int* __restrict__ bucket)
{
    int e = blockIdx.x * 256 + threadIdx.x;
    if (e >= N_EDGES) return;
    int d = dst[e];
    int pos = atomicAdd(&cnt[d], 1);
    if (pos < BCAP) bucket[(long long)d * BCAP + pos] = src[e];
}

// ---------------- fused GIN layer ----------------
// ROWS rows/block; TPR=256/ROWS threads/row, FPT=K/TPR features each.
template<int K, int ROWS, bool POOL>
__global__ __launch_bounds__(256, 6) void fused_layer_k(
    const ushort_t* __restrict__ xin, const int* __restrict__ cnt,
    const int* __restrict__ bucket, const ushort_t* __restrict__ wp1,
    const float* __restrict__ b1, const float* __restrict__ gamma,
    const float* __restrict__ beta, const float* __restrict__ rmean,
    const float* __restrict__ rvar, const ushort_t* __restrict__ wp2,
    const float* __restrict__ b2, ushort_t* __restrict__ out,
    const int* __restrict__ batch, float* __restrict__ pooled)
{
    constexpr int KS1 = K / 32;
    constexpr int KS2 = 4;
    constexpr int LDA = K + 8;
    constexpr int LDT = HDIM + 8;
    constexpr int TPR = 256 / ROWS;
    constexpr int FPT = K / TPR;
    constexpr int NV  = FPT / 8;
    constexpr int MT  = ROWS / 32;
    __shared__ ushort_t A_lds[ROWS * LDT];
    __shared__ int batch_l[ROWS];

    const int tid  = threadIdx.x;
    const int lane = tid & 63;
    const int wid  = tid >> 6;
    const int wm   = wid >> 1;
    const int wn   = wid & 1;
    const long long m0 = (long long)blockIdx.x * ROWS;

    if (POOL && tid < ROWS) batch_l[tid] = batch[m0 + tid];

    // ---- gather-stage: TPR threads/row, FPT features each, f32 accumulate ----
    {
        const int row = tid / TPR;
        const int fq  = (tid % TPR) * FPT;
        long long n = m0 + row;
        float acc[FPT];
        {
            const uint4* xp = (const uint4*)(xin + n * (long long)K + fq);
            #pragma unroll
            for (int v = 0; v < NV; ++v) {
                uint4 u = xp[v];
                acc[v*8+0]=bf2f(u.x&0xffff); acc[v*8+1]=bf2f(u.x>>16);
                acc[v*8+2]=bf2f(u.y&0xffff); acc[v*8+3]=bf2f(u.y>>16);
                acc[v*8+4]=bf2f(u.z&0xffff); acc[v*8+5]=bf2f(u.z>>16);
                acc[v*8+6]=bf2f(u.w&0xffff); acc[v*8+7]=bf2f(u.w>>16);
            }
        }
        int dg = cnt[n]; dg = (dg < BCAP) ? dg : BCAP;
        const long long p0 = n * (long long)BCAP;
        for (int p = 0; p < dg; ++p) {
            long long s = bucket[p0 + p];
            const uint4* sp = (const uint4*)(xin + s * (long long)K + fq);
            uint4 u[NV];
            #pragma unroll
            for (int v = 0; v < NV; ++v) u[v] = sp[v];
            #pragma unroll
            for (int v = 0; v < NV; ++v) {
                acc[v*8+0]+=bf2f(u[v].x&0xffff); acc[v*8+1]+=bf2f(u[v].x>>16);
                acc[v*8+2]+=bf2f(u[v].y&0xffff); acc[v*8+3]+=bf2f(u[v].y>>16);
                acc[v*8+4]+=bf2f(u[v].z&0xffff); acc[v*8+5]+=bf2f(u[v].z>>16);
                acc[v*8+6]+=bf2f(u[v].w&0xffff); acc[v*8+7]+=bf2f(u[v].w>>16);
            }
        }
        #pragma unroll
        for (int f = 0; f < FPT; f += 2) {
            uint_t pk = (uint_t)f2bf(acc[f]) | ((uint_t)f2bf(acc[f+1]) << 16);
            *reinterpret_cast<uint_t*>(&A_lds[row * LDA + fq + f]) = pk;
        }
    }
    __syncthreads();

    // ---- GEMM1 K-loop (B streamed per-ks) ----
    f32x4 acc1[MT][4] = {};
    #pragma unroll 1
    for (int ks = 0; ks < KS1; ++ks) {
        short8 bfrag[4];
        #pragma unroll
        for (int nt = 0; nt < 4; ++nt)
            bfrag[nt] = *reinterpret_cast<const short8*>(
                wp1 + (((((wn * 4 + nt) * KS1) + ks) * 64 + lane) << 3));
        short8 afrag[MT];
        #pragma unroll
        for (int mt = 0; mt < MT; ++mt) {
            int row = (wm * MT + mt) * 16 + (lane & 15);
            int c   = ks * 32 + ((lane >> 4) << 3);
            afrag[mt] = *reinterpret_cast<const short8*>(&A_lds[row * LDA + c]);
        }
        #pragma unroll
        for (int mt = 0; mt < MT; ++mt)
            #pragma unroll
            for (int nt = 0; nt < 4; ++nt)
                acc1[mt][nt] = __builtin_amdgcn_mfma_f32_16x16x32_bf16(
                    afrag[mt], bfrag[nt], acc1[mt][nt], 0, 0, 0);
    }
    __syncthreads();

    // ---- BN + ReLU -> T ----
    #pragma unroll
    for (int nt = 0; nt < 4; ++nt) {
        int c = wn * 64 + nt * 16 + (lane & 15);
        float rs = rsqrtf(rvar[c] + BN_EPS);
        float scale = gamma[c] * rs;
        float shift = (b1[c] - rmean[c]) * scale + beta[c];
        #pragma unroll
        for (int mt = 0; mt < MT; ++mt) {
            int rowb = (wm * MT + mt) * 16 + ((lane >> 4) << 2);
            #pragma unroll
            for (int r = 0; r < 4; ++r) {
                float v = fmaxf(acc1[mt][nt][r] * scale + shift, 0.f);
                A_lds[(rowb + r) * LDT + c] = f2bf(v);
            }
        }
    }
    __syncthreads();

    // ---- GEMM2 K-loop ----
    f32x4 acc2[MT][4] = {};
    #pragma unroll 1
    for (int ks = 0; ks < KS2; ++ks) {
        short8 bfrag[4];
        #pragma unroll
        for (int nt = 0; nt < 4; ++nt)
            bfrag[nt] = *reinterpret_cast<const short8*>(
                wp2 + (((((wn * 4 + nt) * KS2) + ks) * 64 + lane) << 3));
        short8 afrag[MT];
        #pragma unroll
        for (int mt = 0; mt < MT; ++mt) {
            int row = (wm * MT + mt) * 16 + (lane & 15);
            int c   = ks * 32 + ((lane >> 4) << 3);
            afrag[mt] = *reinterpret_cast<const short8*>(&A_lds[row * LDT + c]);
        }
        #pragma unroll
        for (int mt = 0; mt < MT; ++mt)
            #pragma unroll
            for (int nt = 0; nt < 4; ++nt)
                acc2[mt][nt] = __builtin_amdgcn_mfma_f32_16x16x32_bf16(
                    afrag[mt], bfrag[nt], acc2[mt][nt], 0, 0, 0);
    }

    if (!POOL) {
        #pragma unroll
        for (int nt = 0; nt < 4; ++nt) {
            int c = wn * 64 + nt * 16 + (lane & 15);
            float bias = b2[c];
            #pragma unroll
            for (int mt = 0; mt < MT; ++mt) {
                long long rowb = m0 + (wm * MT + mt) * 16 + ((lane >> 4) << 2);
                #pragma unroll
                for (int r = 0; r < 4; ++r) {
                    float v = fmaxf(acc2[mt][nt][r] + bias, 0.f);
                    out[(rowb + r) * HDIM + c] = f2bf(v);
                }
            }
        }
    } else {
        __syncthreads();
        #pragma unroll
        for (int nt = 0; nt < 4; ++nt) {
            int c = wn * 64 + nt * 16 + (lane & 15);
            float bias = b2[c];
            #pragma unroll
            for (int mt = 0; mt < MT; ++mt) {
                int rowb = (wm * MT + mt) * 16 + ((lane >> 4) << 2);
                #pragma unroll
                for (int r = 0; r < 4; ++r) {
                    float v = fmaxf(acc2[mt][nt][r] + bias, 0.f);
                    A_lds[(rowb + r) * LDT + c] = f2bf(v);
                }
            }
        }
        __syncthreads();
        if (tid < HDIM) {
            int colw = tid;
            int curb = batch_l[0];
            float s = 0.f;
            #pragma unroll 8
            for (int r = 0; r < ROWS; ++r) {
                int b = batch_l[r];
                if (b != curb) {
                    atomicAdd(&pooled[(long long)curb * HDIM + colw], s);
                    curb = b; s = 0.f;
                }
                s += bf2f(A_lds[r * LDT + colw]);
            }
            atomicAdd(&pooled[(long long)curb * HDIM + colw], s);
        }
    }
}

// ---------------- head ----------------
__global__ __launch_bounds__(64) void fc_head_k(
    const float* __restrict__ pooled,
    const float* __restrict__ w_fc1, const float* __restrict__ b_fc1,
    const float* __restrict__ w_fc2, const float* __restrict__ b_fc2,
    float* __restrict__ out)
{
    int g = blockIdx.x;
    int j = threadIdx.x;   // 0..63
    __shared__ float p[HDIM];
    p[j]      = pooled[(long long)g * HDIM + j];
    p[j + 64] = pooled[(long long)g * HDIM + j + 64];
    __syncthreads();

    float acc = b_fc1[j];
    #pragma unroll 8
    for (int k = 0; k < HDIM; ++k) acc += p[k] * w_fc1[k * 64 + j];
    acc = fmaxf(acc, 0.f);

    float v = acc * w_fc2[j];
    #pragma unroll
    for (int off = 32; off > 0; off >>= 1) v += __shfl_down(v, off, 64);
    if (j == 0) out[g] = v + b_fc2[0];
}

extern "C" void kernel_launch(void* const* d_in, const int* in_sizes, int n_in,
                              void* d_out, int out_size, void* d_ws, size_t ws_size,
                              hipStream_t stream) {
    const float* x     = (const float*)d_in[0];
    const int*   ei    = (const int*)d_in[1];
    const int*   src   = ei;                // edge_index[0]
    const int*   dst   = ei + N_EDGES;      // edge_index[1]
    const int*   batch = (const int*)d_in[3];
    const float* L[3][8];
    for (int l = 0; l < 3; ++l)
        for (int p = 0; p < 8; ++p)
            L[l][p] = (const float*)d_in[4 + 8 * l + p];
    const float* w_fc1 = (const float*)d_in[30];
    const float* b_fc1 = (const float*)d_in[31];
    const float* w_fc2 = (const float*)d_in[32];
    const float* b_fc2 = (const float*)d_in[33];
    float* out = (float*)d_out;

    // ---- workspace layout (bytes); pooled|cnt contiguous (zeroed in prep) ----
    char* base = (char*)d_ws;
    ushort_t* hA     = (ushort_t*)(base);                 // bf16 [N,128] 51.2 MB
    ushort_t* hB     = (ushort_t*)(base + 51200000);      // bf16 [N,128] 51.2 MB
    ushort_t* xbf    = (ushort_t*)(base + 102400000);     // bf16 [N,32] 12.8 MB
    float*    pooled = (float*)   (base + 115200000);     // f32 [G,128] 5.12 MB
    int*      cnt    = (int*)     (base + 120320000);     // 800 KB (after pooled)
    int*      bucket = (int*)     (base + 121120000);     // 200k*32*4 = 25.6 MB
    ushort_t* wp     = (ushort_t*)(base + 146720000);     // 172 KB

    ushort_t* wp1_1 = wp;
    ushort_t* wp2_1 = wp + 4096;
    ushort_t* wp1_2 = wp + 20480;
    ushort_t* wp2_2 = wp + 36864;
    ushort_t* wp1_3 = wp + 53248;
    ushort_t* wp2_3 = wp + 69632;

    const int NB_EDGE = (N_EDGES + 255) / 256; // 2344

    // ---- prep: zeros + weight permutes + x->bf16 ----
    prep_k<<<(PREP_Z + 255) / 256, 256, 0, stream>>>(
        L[0][0], L[0][6], L[1][0], L[1][6], L[2][0], L[2][6], wp, x, xbf,
        (uint_t*)pooled);

    // ---- adjacency build: single kernel ----
    fill_bucket_k<<<NB_EDGE, 256, 0, stream>>>(src, dst, cnt, bucket);

    // ---- 3 fused layers ----
    fused_layer_k<F_NODE, 64, false><<<N_NODES / 64, 256, 0, stream>>>(
        xbf, cnt, bucket, wp1_1, L[0][1], L[0][2], L[0][3], L[0][4], L[0][5],
        wp2_1, L[0][7], hA, nullptr, nullptr);
    fused_layer_k<HDIM, 32, false><<<N_NODES / 32, 256, 0, stream>>>(
        hA, cnt, bucket, wp1_2, L[1][1], L[1][2], L[1][3], L[1][4], L[1][5],
        wp2_2, L[1][7], hB, nullptr, nullptr);
    fused_layer_k<HDIM, 32, true><<<N_NODES / 32, 256, 0, stream>>>(
        hB, cnt, bucket, wp1_3, L[2][1], L[2][2], L[2][3], L[2][4], L[2][5],
        wp2_3, L[2][7], nullptr, batch, pooled);

    // ---- head ----
    fc_head_k<<<N_GRAPHS, 64, 0, stream>>>(pooled, w_fc1, b_fc1, w_fc2, b_fc2, out);
}